// Round 7
// baseline (409.534 us; speedup 1.0000x reference)
//
#include <hip/hip_runtime.h>
#include <hip/hip_bf16.h>

#define N_NODES 100000
#define N_EDGES 1600000
#define D 128
#define NB 1563            // ceil(100000/64) buckets of 64 nodes
#define PB 512             // partition blocks
#define CHUNK 3125         // PB*CHUNK == N_EDGES
#define SCANL (NB * PB)    // 800256 count-matrix elements
#define SGRID (SCANL / 512) // 1563 scan blocks per array (512 elems/block); == NB since PB==512
#define SENT N_NODES       // sentinel (zero) row index
#define ECAP 2560          // LDS elist capacity per bucket (mean 1024 + pad <= 192)

typedef __attribute__((ext_vector_type(8))) short bf16x8;
typedef __attribute__((ext_vector_type(4))) float f32x4;

__device__ __forceinline__ float bf2f(unsigned short u) {
    unsigned int x = ((unsigned int)u) << 16;
    return __builtin_bit_cast(float, x);
}
__device__ __forceinline__ unsigned short f2bf(float f) {
    unsigned int x = __builtin_bit_cast(unsigned int, f);
    x += 0x7fffu + ((x >> 16) & 1u);   // round-to-nearest-even
    return (unsigned short)(x >> 16);
}
__device__ __forceinline__ void accum8(float* acc, uint4 x) {
    acc[0] += bf2f((unsigned short)x.x); acc[1] += bf2f((unsigned short)(x.x >> 16));
    acc[2] += bf2f((unsigned short)x.y); acc[3] += bf2f((unsigned short)(x.y >> 16));
    acc[4] += bf2f((unsigned short)x.z); acc[5] += bf2f((unsigned short)(x.z >> 16));
    acc[6] += bf2f((unsigned short)x.w); acc[7] += bf2f((unsigned short)(x.w >> 16));
}
// column permutation: co-XCD blocks (b%8 equal under round-robin dispatch) get adjacent
// count-matrix columns, so partial-line writes in k_pscatter stay XCD-local.
__device__ __forceinline__ int XP(int b) { return ((b & 7) << 6) | (b >> 3); }

// ---- P1: per-block LDS bucket histograms (dst>>6 and src>>6), no global atomics ----
__global__ __launch_bounds__(1024) void k_pcount(const int* __restrict__ src, const int* __restrict__ dst,
                                                 int* __restrict__ cntD, int* __restrict__ cntS) {
    __shared__ int hd[NB];
    __shared__ int hs[NB];
    int t = threadIdx.x, blk = blockIdx.x;
    int col = XP(blk);
    for (int i = t; i < NB; i += 1024) { hd[i] = 0; hs[i] = 0; }
    __syncthreads();
    int base = blk * CHUNK;
    for (int i = t; i < CHUNK; i += 1024) {
        int e = base + i;
        atomicAdd(&hd[dst[e] >> 6], 1);
        atomicAdd(&hs[src[e] >> 6], 1);
    }
    __syncthreads();
    for (int i = t; i < NB; i += 1024) {
        cntD[i * PB + col] = hd[i];
        cntS[i * PB + col] = hs[i];
    }
}

// ---- fused D+S exclusive scan pass 1; 512 elements per block; bs[blk] = block total ----
__global__ void k_scanDS1(int* __restrict__ cntD, int* __restrict__ cntS, int* __restrict__ bs) {
    __shared__ int tmp[256];
    int t = threadIdx.x;
    int which = (blockIdx.x >= SGRID) ? 1 : 0;
    int blk = blockIdx.x - which * SGRID;
    int* a = which ? cntS : cntD;
    int base = blk * 512;
    int a0 = a[base + 2 * t], a1 = a[base + 2 * t + 1];
    int s = a0 + a1;
    tmp[t] = s; __syncthreads();
    for (int off = 1; off < 256; off <<= 1) {
        int x = (t >= off) ? tmp[t - off] : 0;
        __syncthreads();
        tmp[t] += x;
        __syncthreads();
    }
    int excl = tmp[t] - s;
    a[base + 2 * t] = excl;
    a[base + 2 * t + 1] = excl + a0;
    if (t == 255) bs[blockIdx.x] = tmp[255];
}

__global__ void k_scan2two(int* __restrict__ bs) {  // 2 blocks, 1024 threads; each scans SGRID entries
    __shared__ int tmp[1024];
    int t = threadIdx.x;
    int base = blockIdx.x * SGRID;
    int i0 = 2 * t, i1 = 2 * t + 1;
    int a = (i0 < SGRID) ? bs[base + i0] : 0;
    int b = (i1 < SGRID) ? bs[base + i1] : 0;
    int s = a + b;
    tmp[t] = s; __syncthreads();
    for (int off = 1; off < 1024; off <<= 1) {
        int x = (t >= off) ? tmp[t - off] : 0;
        __syncthreads();
        tmp[t] += x;
        __syncthreads();
    }
    int excl = tmp[t] - s;
    if (i0 < SGRID) bs[base + i0] = excl;
    if (i1 < SGRID) bs[base + i1] = excl + a;
}

// NOTE: no scanDS3 pass — since PB==512, scan-block i covers matrix rows [i*512,(i+1)*512),
// so consumers fold the block offset: scanD[i*PB+col] + bsD[i].

// ---- P2: scatter edges into bucket order; positions from scanned matrices + LDS cursors ----
__global__ __launch_bounds__(1024) void k_pscatter(const int* __restrict__ src, const int* __restrict__ dst,
                                                   const int* __restrict__ scanD, const int* __restrict__ scanS,
                                                   const int* __restrict__ bs,
                                                   unsigned int* __restrict__ pairD, unsigned char* __restrict__ srcS) {
    __shared__ int od[NB];
    __shared__ int osx[NB];
    int t = threadIdx.x, blk = blockIdx.x;
    int col = XP(blk);
    for (int i = t; i < NB; i += 1024) {
        od[i] = scanD[i * PB + col] + bs[i];
        osx[i] = scanS[i * PB + col] + bs[SGRID + i];
    }
    __syncthreads();
    int base = blk * CHUNK;
    for (int i = t; i < CHUNK; i += 1024) {
        int e = base + i;
        int s = src[e], d = dst[e];
        int pd = atomicAdd(&od[d >> 6], 1);
        pairD[pd] = ((unsigned int)(d & 63) << 26) | (unsigned int)s;
        int ps = atomicAdd(&osx[s >> 6], 1);
        srcS[ps] = (unsigned char)(s & 63);
    }
}

// ---- P3: out-degree per node from src-bucketed bytes -> norm_src ----
__global__ __launch_bounds__(256) void k_normsrc(const unsigned char* __restrict__ srcS,
                                                 const int* __restrict__ scanS, const int* __restrict__ bs,
                                                 float* __restrict__ ns) {
    __shared__ int c[64];
    int b = blockIdx.x, t = threadIdx.x;
    if (t < 64) c[t] = 0;
    __syncthreads();
    int beg = scanS[b * PB] + bs[SGRID + b];
    int end = (b < NB - 1) ? (scanS[(b + 1) * PB] + bs[SGRID + b + 1]) : N_EDGES;
    for (int i = beg + t; i < end; i += 256) atomicAdd(&c[srcS[i]], 1);
    __syncthreads();
    if (t < 64) {
        int g = b * 64 + t;
        if (g < N_NODES) {
            int a = c[t]; if (a < 1) a = 1;
            ns[g] = rsqrtf((float)a);
        }
    }
}

// ---- fp32 -> bf16 conversion fused with norm_src pre-scaling; also zeroes SENT rows ----
__global__ void k_cvt(const float* __restrict__ x, const float* __restrict__ ns,
                      unsigned short* __restrict__ hA, unsigned short* __restrict__ hB, int n4) {
    int i = blockIdx.x * 256 + threadIdx.x;
    if (i < n4) {
        int row = i >> 5;                    // D/4 = 32 float4 per row
        float sc = ns[row];
        const float4 v = ((const float4*)x)[i];
        unsigned int lo = (unsigned int)f2bf(v.x * sc) | ((unsigned int)f2bf(v.y * sc) << 16);
        unsigned int hi = (unsigned int)f2bf(v.z * sc) | ((unsigned int)f2bf(v.w * sc) << 16);
        ((uint2*)hA)[i] = make_uint2(lo, hi);
    } else if (i < n4 + 64) {
        int j = i - n4;                      // zero sentinel rows of both buffers
        uint2 z = {0u, 0u};
        if (j < 32) ((uint2*)(hA + (size_t)SENT * D))[j] = z;
        else        ((uint2*)(hB + (size_t)SENT * D))[j - 32] = z;
    }
}

// ---- all 3 W (fp32) -> bf16 B-fragment-contiguous layout, one launch ----
__global__ void k_transw3(const float* __restrict__ W0, const float* __restrict__ W1,
                          const float* __restrict__ W2, unsigned short* __restrict__ Wt) {
    int gid = blockIdx.x * 256 + threadIdx.x;   // 0..6143
    if (gid >= 3 * 2048) return;
    int layer = gid >> 11;
    int di8   = gid & 2047;
    const float* W = (layer == 0) ? W0 : ((layer == 1) ? W1 : W2);
    int di   = di8 * 8;
    int lane = di8 & 63;
    int nt   = (di8 >> 6) & 7;
    int kc   = di8 >> 9;
    int quad = lane >> 4, col = lane & 15;
    unsigned short v[8];
#pragma unroll
    for (int j = 0; j < 8; j++) {
        int k = kc * 32 + quad * 8 + j;
        int nn = nt * 16 + col;
        v[j] = f2bf(W[k * 128 + nn]);
    }
    unsigned short* dp = Wt + (size_t)layer * 16384 + di;
#pragma unroll
    for (int j = 0; j < 8; j++) dp[j] = v[j];
}

// swizzled A-tile byte address: row-major [64][128] bf16, 16B blocks XOR'd by (row&7)
__device__ __forceinline__ int aswz(int row, int byte16) {
    return row * 256 + (byte16 ^ ((row & 7) << 4));
}

// ---- fused layer: in-LDS bucket sort (round-0 style, hidden under gather latency)
//      -> branch-free pad-4 gather -> LDS A-tile -> MFMA GEMM -> epilogue ----
__global__ __launch_bounds__(256) void k_fused(const unsigned short* __restrict__ hin,
        const unsigned int* __restrict__ pairD, const int* __restrict__ scanD, const int* __restrict__ bsD,
        const float* __restrict__ nsp,
        const unsigned short* __restrict__ Wt, const float* __restrict__ bias,
        unsigned short* __restrict__ Cb, float* __restrict__ Cf, int M) {
    __shared__ int elist[ECAP];
    __shared__ int cnt[64], off[64], cur[64];
    __shared__ int ptotS;
    __shared__ unsigned short lA[64 * 128];
    int b = blockIdx.x, t = threadIdx.x;
    int lane = t & 63, wave = t >> 6;          // wave 0..3
    int sub = lane >> 4, col = lane & 15;

    int beg = scanD[b * PB] + bsD[b];
    int end = (b < NB - 1) ? (scanD[(b + 1) * PB] + bsD[b + 1]) : N_EDGES;
    int n = end - beg;

    if (t < 64) cnt[t] = 0;
    __syncthreads();
    // count per local dst
    for (int i = t; i < n; i += 256) atomicAdd(&cnt[pairD[beg + i] >> 26], 1);
    __syncthreads();
    // pad-4 exclusive scan (wave 0)
    if (wave == 0) {
        int v = cnt[lane];
        int pc = (v + 3) & ~3;
        int x = pc;
        for (int o = 1; o < 64; o <<= 1) { int y = __shfl_up(x, o); if (lane >= o) x += y; }
        off[lane] = x - pc;
        cur[lane] = x - pc;
        if (lane == 63) ptotS = x;
    }
    __syncthreads();
    int ptot = ptotS; if (ptot > ECAP) ptot = ECAP;
    // sentinel pre-fill (pad slots stay = SENT -> zero row)
    for (int i = t; i < ptot; i += 256) elist[i] = SENT;
    __syncthreads();
    // scatter into sorted positions
    for (int i = t; i < n; i += 256) {
        unsigned int p = pairD[beg + i];
        int pos = atomicAdd(&cur[p >> 26], 1);
        if (pos < ECAP) elist[pos] = (int)(p & 0x3FFFFFFu);
    }
    __syncthreads();

    // ---- phase A: wave-per-row gather (pad-4 branch-free, 4 uint4 in flight) ----
    for (int r = wave; r < 64; r += 4) {
        int ro = off[r];
        int dgr = cnt[r];
        int re = ro + ((dgr + 3) & ~3);
        if (re > ECAP) re = ECAP;
        if (ro > ECAP) ro = ECAP;
        float acc[8];
#pragma unroll
        for (int j = 0; j < 8; j++) acc[j] = 0.f;
        int e = ro;
        for (; e + 16 <= re; e += 16) {
            int s0 = elist[e + sub];
            int s1 = elist[e + 4 + sub];
            int s2 = elist[e + 8 + sub];
            int s3 = elist[e + 12 + sub];
            uint4 x0 = *(const uint4*)(hin + (size_t)s0 * D + col * 8);
            uint4 x1 = *(const uint4*)(hin + (size_t)s1 * D + col * 8);
            uint4 x2 = *(const uint4*)(hin + (size_t)s2 * D + col * 8);
            uint4 x3 = *(const uint4*)(hin + (size_t)s3 * D + col * 8);
            accum8(acc, x0); accum8(acc, x1); accum8(acc, x2); accum8(acc, x3);
        }
        for (; e < re; e += 4) {
            int s = elist[e + sub];
            uint4 x = *(const uint4*)(hin + (size_t)s * D + col * 8);
            accum8(acc, x);
        }
#pragma unroll
        for (int j = 0; j < 8; j++) {
            acc[j] += __shfl_xor(acc[j], 16);
            acc[j] += __shfl_xor(acc[j], 32);
        }
        if (sub == 0) {
            int d2 = dgr; if (d2 < 1) d2 = 1;
            float s = rsqrtf((float)d2);
            uint4 o;
            o.x = (unsigned int)f2bf(acc[0] * s) | ((unsigned int)f2bf(acc[1] * s) << 16);
            o.y = (unsigned int)f2bf(acc[2] * s) | ((unsigned int)f2bf(acc[3] * s) << 16);
            o.z = (unsigned int)f2bf(acc[4] * s) | ((unsigned int)f2bf(acc[5] * s) << 16);
            o.w = (unsigned int)f2bf(acc[6] * s) | ((unsigned int)f2bf(acc[7] * s) << 16);
            *(uint4*)((char*)lA + aswz(r, col * 16)) = o;
        }
    }
    __syncthreads();

    // ---- phase B: MFMA GEMM; 4 waves = 4 row-tiles; 2 N-half passes keep VGPR <= 64 ----
    int row0 = b * 64 + wave * 16;
    float nsv[4];
    if (Cb) {
#pragma unroll
        for (int r = 0; r < 4; r++) {
            int rr = row0 + sub * 4 + r;
            nsv[r] = (rr < M) ? nsp[rr] : 1.f;
        }
    }
#pragma unroll
    for (int half = 0; half < 2; half++) {
        f32x4 acc2[4];
#pragma unroll
        for (int i = 0; i < 4; i++) acc2[i] = (f32x4){0.f, 0.f, 0.f, 0.f};
        int lr = wave * 16 + col;
#pragma unroll
        for (int kc = 0; kc < 4; kc++) {
            bf16x8 af = *(const bf16x8*)((const char*)lA + aswz(lr, kc * 64 + sub * 16));
#pragma unroll
            for (int j = 0; j < 4; j++) {
                int nt = half * 4 + j;
                bf16x8 bfr = *(const bf16x8*)(Wt + ((size_t)(kc * 8 + nt) * 64 + lane) * 8);
                acc2[j] = __builtin_amdgcn_mfma_f32_16x16x32_bf16(af, bfr, acc2[j], 0, 0, 0);
            }
        }
#pragma unroll
        for (int j = 0; j < 4; j++) {
            int nt = half * 4 + j;
            float bv = bias[nt * 16 + col];
#pragma unroll
            for (int r = 0; r < 4; r++) {
                int rr = row0 + sub * 4 + r;
                if (rr < M) {
                    float v = acc2[j][r] + bv;
                    if (Cf) {
                        Cf[(size_t)rr * D + nt * 16 + col] = v;
                    } else {
                        v = fmaxf(v, 0.f) * nsv[r];
                        Cb[(size_t)rr * D + nt * 16 + col] = f2bf(v);
                    }
                }
            }
        }
    }
}

extern "C" void kernel_launch(void* const* d_in, const int* in_sizes, int n_in,
                              void* d_out, int out_size, void* d_ws, size_t ws_size,
                              hipStream_t stream) {
    const float* x  = (const float*)d_in[0];
    const int* src = (const int*)d_in[1];
    const int* dst = (const int*)d_in[2];
    const float* Wl[3] = {(const float*)d_in[3], (const float*)d_in[5], (const float*)d_in[7]};
    const float* Bl[3] = {(const float*)d_in[4], (const float*)d_in[6], (const float*)d_in[8]};

    const int N = N_NODES;
    const int Mpad = ((N + 63) / 64) * 64;   // 100032 rows (includes SENT row)
    const size_t HBYTES = (size_t)Mpad * D * 2;  // 25,608,192

    char* ws = (char*)d_ws;

    // ---- aliased region: hB overlays buffers that die before layer 0 writes hB ----
    unsigned short* hB = (unsigned short*)ws;                 // [0, HBYTES)
    int* cntS = (int*)ws;                                     // 3.2 MB (dead after k_normsrc)
    unsigned char* srcS = (unsigned char*)(ws + (size_t)SCANL * 4);  // 1.6 MB (dead after k_normsrc)
    // aliased use: ~4.8 MB < HBYTES ✓

    // ---- persistent region after hB (pairD/cntD/bs live through all fused layers) ----
    size_t o = HBYTES;
    auto take = [&](size_t bytes) -> void* {
        o = (o + 255) & ~(size_t)255;
        void* p = ws + o;
        o += bytes;
        return p;
    };
    float* norm_src = (float*)take((size_t)N * 4);
    unsigned int* pairD = (unsigned int*)take((size_t)N_EDGES * 4);    // 6.4 MB
    int* cntD = (int*)take((size_t)SCANL * 4);                         // 3.2 MB (scanD)
    int* bs   = (int*)take((size_t)2 * SGRID * 4);                     // 12.5 KB
    unsigned short* Wt = (unsigned short*)take((size_t)3 * 128 * 128 * 2);
    unsigned short* hA = (unsigned short*)take(HBYTES);

    // partition preprocessing (LDS atomics only; no scan3 pass — offsets folded into consumers)
    k_pcount<<<PB, 1024, 0, stream>>>(src, dst, cntD, cntS);
    k_scanDS1<<<2 * SGRID, 256, 0, stream>>>(cntD, cntS, bs);
    k_scan2two<<<2, 1024, 0, stream>>>(bs);
    k_pscatter<<<PB, 1024, 0, stream>>>(src, dst, cntD, cntS, bs, pairD, srcS);
    k_normsrc<<<NB, 256, 0, stream>>>(srcS, cntS, bs, norm_src);

    // x (fp32) * norm_src -> bf16; also zero SENT rows of hA/hB
    k_cvt<<<(N * 32 + 64 + 255) / 256, 256, 0, stream>>>(x, norm_src, hA, hB, N * 32);
    // all three weight transposes in one launch
    k_transw3<<<24, 256, 0, stream>>>(Wl[0], Wl[1], Wl[2], Wt);

    // fused layers: in-LDS sort + gather + GEMM + activation(+prescale) per launch
    k_fused<<<NB, 256, 0, stream>>>(hA, pairD, cntD, bs, norm_src, Wt,         Bl[0], hB, nullptr, N);
    k_fused<<<NB, 256, 0, stream>>>(hB, pairD, cntD, bs, norm_src, Wt + 16384, Bl[1], hA, nullptr, N);
    k_fused<<<NB, 256, 0, stream>>>(hA, pairD, cntD, bs, norm_src, Wt + 32768, Bl[2], nullptr, (float*)d_out, N);
}

// Round 8
// 375.325 us; speedup vs baseline: 1.0911x; 1.0911x over previous
//
#include <hip/hip_runtime.h>
#include <hip/hip_bf16.h>

#define N_NODES 100000
#define N_EDGES 1600000
#define D 128
#define NB 1563            // ceil(100000/64) buckets of 64 nodes
#define PB 512             // partition blocks
#define CHUNK 3125         // PB*CHUNK == N_EDGES
#define SCANL (NB * PB)    // 800256 count-matrix elements
#define SGRID (SCANL / 512) // 1563 scan blocks per array (512 elems/block); == NB since PB==512
#define SENT N_NODES       // sentinel (zero) row index
#define ECAP_PAD (N_EDGES + 256 * NB)  // 2000128: padded CSR capacity (pad-4 slack <= 192/bucket)
#define BCAP 2816          // LDS staging capacity per bucket in k_bsortpad

typedef __attribute__((ext_vector_type(8))) short bf16x8;
typedef __attribute__((ext_vector_type(4))) float f32x4;

__device__ __forceinline__ float bf2f(unsigned short u) {
    unsigned int x = ((unsigned int)u) << 16;
    return __builtin_bit_cast(float, x);
}
__device__ __forceinline__ unsigned short f2bf(float f) {
    unsigned int x = __builtin_bit_cast(unsigned int, f);
    x += 0x7fffu + ((x >> 16) & 1u);   // round-to-nearest-even
    return (unsigned short)(x >> 16);
}
__device__ __forceinline__ void accum8(float* acc, uint4 x) {
    acc[0] += bf2f((unsigned short)x.x); acc[1] += bf2f((unsigned short)(x.x >> 16));
    acc[2] += bf2f((unsigned short)x.y); acc[3] += bf2f((unsigned short)(x.y >> 16));
    acc[4] += bf2f((unsigned short)x.z); acc[5] += bf2f((unsigned short)(x.z >> 16));
    acc[6] += bf2f((unsigned short)x.w); acc[7] += bf2f((unsigned short)(x.w >> 16));
}
// column permutation: co-XCD blocks (b%8 equal under round-robin dispatch) get adjacent
// count-matrix columns, so partial-line writes in k_pscatter stay XCD-local.
__device__ __forceinline__ int XP(int b) { return ((b & 7) << 6) | (b >> 3); }

// ---- P1: per-block LDS bucket histograms (dst>>6 and src>>6), no global atomics ----
__global__ __launch_bounds__(1024) void k_pcount(const int* __restrict__ src, const int* __restrict__ dst,
                                                 int* __restrict__ cntD, int* __restrict__ cntS) {
    __shared__ int hd[NB];
    __shared__ int hs[NB];
    int t = threadIdx.x, blk = blockIdx.x;
    int col = XP(blk);
    for (int i = t; i < NB; i += 1024) { hd[i] = 0; hs[i] = 0; }
    __syncthreads();
    int base = blk * CHUNK;
    for (int i = t; i < CHUNK; i += 1024) {
        int e = base + i;
        atomicAdd(&hd[dst[e] >> 6], 1);
        atomicAdd(&hs[src[e] >> 6], 1);
    }
    __syncthreads();
    for (int i = t; i < NB; i += 1024) {
        cntD[i * PB + col] = hd[i];
        cntS[i * PB + col] = hs[i];
    }
}

// ---- fused D+S exclusive scan pass 1; 512 elements per block; bs[blk] = block total ----
__global__ void k_scanDS1(int* __restrict__ cntD, int* __restrict__ cntS, int* __restrict__ bs) {
    __shared__ int tmp[256];
    int t = threadIdx.x;
    int which = (blockIdx.x >= SGRID) ? 1 : 0;
    int blk = blockIdx.x - which * SGRID;
    int* a = which ? cntS : cntD;
    int base = blk * 512;
    int a0 = a[base + 2 * t], a1 = a[base + 2 * t + 1];
    int s = a0 + a1;
    tmp[t] = s; __syncthreads();
    for (int off = 1; off < 256; off <<= 1) {
        int x = (t >= off) ? tmp[t - off] : 0;
        __syncthreads();
        tmp[t] += x;
        __syncthreads();
    }
    int excl = tmp[t] - s;
    a[base + 2 * t] = excl;
    a[base + 2 * t + 1] = excl + a0;
    if (t == 255) bs[blockIdx.x] = tmp[255];
}

__global__ void k_scan2two(int* __restrict__ bs) {  // 2 blocks, 1024 threads; each scans SGRID entries
    __shared__ int tmp[1024];
    int t = threadIdx.x;
    int base = blockIdx.x * SGRID;
    int i0 = 2 * t, i1 = 2 * t + 1;
    int a = (i0 < SGRID) ? bs[base + i0] : 0;
    int b = (i1 < SGRID) ? bs[base + i1] : 0;
    int s = a + b;
    tmp[t] = s; __syncthreads();
    for (int off = 1; off < 1024; off <<= 1) {
        int x = (t >= off) ? tmp[t - off] : 0;
        __syncthreads();
        tmp[t] += x;
        __syncthreads();
    }
    int excl = tmp[t] - s;
    if (i0 < SGRID) bs[base + i0] = excl;
    if (i1 < SGRID) bs[base + i1] = excl + a;
}

// NOTE: no scanDS3 pass — since PB==512, scan-block i covers matrix rows [i*512,(i+1)*512),
// so consumers fold the block offset: scanD[i*PB+col] + bsD[i].

// ---- P2: scatter edges into bucket order; positions from scanned matrices + LDS cursors ----
__global__ __launch_bounds__(1024) void k_pscatter(const int* __restrict__ src, const int* __restrict__ dst,
                                                   const int* __restrict__ scanD, const int* __restrict__ scanS,
                                                   const int* __restrict__ bs,
                                                   unsigned int* __restrict__ pairD, unsigned char* __restrict__ srcS) {
    __shared__ int od[NB];
    __shared__ int osx[NB];
    int t = threadIdx.x, blk = blockIdx.x;
    int col = XP(blk);
    for (int i = t; i < NB; i += 1024) {
        od[i] = scanD[i * PB + col] + bs[i];
        osx[i] = scanS[i * PB + col] + bs[SGRID + i];
    }
    __syncthreads();
    int base = blk * CHUNK;
    for (int i = t; i < CHUNK; i += 1024) {
        int e = base + i;
        int s = src[e], d = dst[e];
        int pd = atomicAdd(&od[d >> 6], 1);
        pairD[pd] = ((unsigned int)(d & 63) << 26) | (unsigned int)s;
        int ps = atomicAdd(&osx[s >> 6], 1);
        srcS[ps] = (unsigned char)(s & 63);
    }
}

// ---- P3: out-degree per node from src-bucketed bytes -> norm_src ----
__global__ __launch_bounds__(256) void k_normsrc(const unsigned char* __restrict__ srcS,
                                                 const int* __restrict__ scanS, const int* __restrict__ bs,
                                                 float* __restrict__ ns) {
    __shared__ int c[64];
    int b = blockIdx.x, t = threadIdx.x;
    if (t < 64) c[t] = 0;
    __syncthreads();
    int beg = scanS[b * PB] + bs[SGRID + b];
    int end = (b < NB - 1) ? (scanS[(b + 1) * PB] + bs[SGRID + b + 1]) : N_EDGES;
    for (int i = beg + t; i < end; i += 256) atomicAdd(&c[srcS[i]], 1);
    __syncthreads();
    if (t < 64) {
        int g = b * 64 + t;
        if (g < N_NODES) {
            int a = c[t]; if (a < 1) a = 1;
            ns[g] = rsqrtf((float)a);
        }
    }
}

// ---- per-bucket counting sort -> PADDED CSR via LDS staging (coalesced esrc writes) ----
__global__ __launch_bounds__(256) void k_bsortpad(const unsigned int* __restrict__ pairD,
                                                  const int* __restrict__ scanD, const int* __restrict__ bs,
                                                  int* __restrict__ esrc,
                                                  int* __restrict__ rowbeg,
                                                  int* __restrict__ degD) {
    __shared__ int cnt[64], off[64], cur[64];
    __shared__ int ptotS;
    __shared__ int stage[BCAP];
    int b = blockIdx.x, t = threadIdx.x;
    int lane = t & 63, wave = t >> 6;
    if (t < 64) cnt[t] = 0;
    __syncthreads();
    int beg = scanD[b * PB] + bs[b];
    int end = (b < NB - 1) ? (scanD[(b + 1) * PB] + bs[b + 1]) : N_EDGES;
    int n = end - beg;
    int base = beg + 256 * b;   // per-bucket region with 256-slot pad slack
    for (int i = t; i < n; i += 256) atomicAdd(&cnt[pairD[beg + i] >> 26], 1);
    __syncthreads();
    if (wave == 0) {
        int v = cnt[lane];
        int pc = (v + 3) & ~3;            // pad each row to multiple of 4
        int x = pc;
        for (int o = 1; o < 64; o <<= 1) { int y = __shfl_up(x, o); if (lane >= o) x += y; }
        off[lane] = x - pc;
        cur[lane] = x - pc;
        if (lane == 63) ptotS = x;        // padded total for this bucket
    }
    __syncthreads();
    int ptot = ptotS; if (ptot > BCAP) ptot = BCAP;
    if (t < 64) {
        int g = b * 64 + t;
        if (g < N_NODES) { rowbeg[g] = base + off[t]; degD[g] = cnt[t]; }
    }
    // sentinel pre-fill of the whole padded region (pads = slots never overwritten)
    for (int i = t; i < ptot; i += 256) stage[i] = SENT;
    __syncthreads();
    for (int i = t; i < n; i += 256) {
        unsigned int p = pairD[beg + i];
        int pos = atomicAdd(&cur[p >> 26], 1);
        if (pos < BCAP) stage[pos] = (int)(p & 0x3FFFFFFu);
    }
    __syncthreads();
    // coalesced write-out
    for (int i = t; i < ptot; i += 256) esrc[base + i] = stage[i];
}

// ---- fp32 -> bf16 conversion fused with norm_src pre-scaling; also zeroes SENT rows ----
__global__ void k_cvt(const float* __restrict__ x, const float* __restrict__ ns,
                      unsigned short* __restrict__ hA, unsigned short* __restrict__ hB, int n4) {
    int i = blockIdx.x * 256 + threadIdx.x;
    if (i < n4) {
        int row = i >> 5;                    // D/4 = 32 float4 per row
        float sc = ns[row];
        const float4 v = ((const float4*)x)[i];
        unsigned int lo = (unsigned int)f2bf(v.x * sc) | ((unsigned int)f2bf(v.y * sc) << 16);
        unsigned int hi = (unsigned int)f2bf(v.z * sc) | ((unsigned int)f2bf(v.w * sc) << 16);
        ((uint2*)hA)[i] = make_uint2(lo, hi);
    } else if (i < n4 + 64) {
        int j = i - n4;                      // zero sentinel rows of both buffers
        uint2 z = {0u, 0u};
        if (j < 32) ((uint2*)(hA + (size_t)SENT * D))[j] = z;
        else        ((uint2*)(hB + (size_t)SENT * D))[j - 32] = z;
    }
}

// ---- all 3 W (fp32) -> bf16 B-fragment-contiguous layout, one launch ----
__global__ void k_transw3(const float* __restrict__ W0, const float* __restrict__ W1,
                          const float* __restrict__ W2, unsigned short* __restrict__ Wt) {
    int gid = blockIdx.x * 256 + threadIdx.x;   // 0..6143
    if (gid >= 3 * 2048) return;
    int layer = gid >> 11;
    int di8   = gid & 2047;
    const float* W = (layer == 0) ? W0 : ((layer == 1) ? W1 : W2);
    int di   = di8 * 8;
    int lane = di8 & 63;
    int nt   = (di8 >> 6) & 7;
    int kc   = di8 >> 9;
    int quad = lane >> 4, col = lane & 15;
    unsigned short v[8];
#pragma unroll
    for (int j = 0; j < 8; j++) {
        int k = kc * 32 + quad * 8 + j;
        int nn = nt * 16 + col;
        v[j] = f2bf(W[k * 128 + nn]);
    }
    unsigned short* dp = Wt + (size_t)layer * 16384 + di;
#pragma unroll
    for (int j = 0; j < 8; j++) dp[j] = v[j];
}

// swizzled A-tile byte address: row-major [64][128] bf16, 16B blocks XOR'd by (row&7)
__device__ __forceinline__ int aswz(int row, int byte16) {
    return row * 256 + (byte16 ^ ((row & 7) << 4));
}

// ---- fused layer: reg-window gather (1-hop chain via shfl-staged indices) -> LDS A-tile ----
// BYTE-IDENTICAL to round 6 (best measured: 72.2 us; 16.9KB LDS, 8 blocks/CU).
__global__ __launch_bounds__(256, 8) void k_fused(const unsigned short* __restrict__ hin,
        const int* __restrict__ esrc, const int* __restrict__ rowbeg, const int* __restrict__ degD,
        const float* __restrict__ nsp,
        const unsigned short* __restrict__ Wt, const float* __restrict__ bias,
        unsigned short* __restrict__ Cb, float* __restrict__ Cf, int M) {
    __shared__ int rb[64];
    __shared__ int dgt[64];
    __shared__ unsigned short lA[64 * 128];
    int b = blockIdx.x, t = threadIdx.x;
    int lane = t & 63, wave = t >> 6;          // wave 0..3
    int sub = lane >> 4, col = lane & 15;

    if (t < 64) {
        int g = b * 64 + t;
        rb[t]  = (g < M) ? rowbeg[g] : 0;
        dgt[t] = (g < M) ? degD[g] : 0;
    }
    __syncthreads();

    // ---- phase A: wave-per-row gather (padded to x4, sentinel row = zeros) ----
    for (int r = wave; r < 64; r += 4) {
        int ro = rb[r];
        int dgr = dgt[r];
        int re = ro + ((dgr + 3) & ~3);
        float acc[8];
#pragma unroll
        for (int j = 0; j < 8; j++) acc[j] = 0.f;
        int e = ro;
        while (e < re) {
            int w = e;                                   // 64-edge register window
            int wl = w + lane;
            int idxreg = (wl < re) ? esrc[wl] : 0;       // coalesced, exec-masked
            int wend = (w + 64 < re) ? (w + 64) : re;
            // main: 16 edges/iter, 4 uint4 in flight, indices via shfl (no global dep)
            for (; e + 16 <= wend; e += 16) {
                int q = e - w;
                int s0 = __shfl(idxreg, q + sub);
                int s1 = __shfl(idxreg, q + 4 + sub);
                int s2 = __shfl(idxreg, q + 8 + sub);
                int s3 = __shfl(idxreg, q + 12 + sub);
                uint4 x0 = *(const uint4*)(hin + (size_t)s0 * D + col * 8);
                uint4 x1 = *(const uint4*)(hin + (size_t)s1 * D + col * 8);
                uint4 x2 = *(const uint4*)(hin + (size_t)s2 * D + col * 8);
                uint4 x3 = *(const uint4*)(hin + (size_t)s3 * D + col * 8);
                accum8(acc, x0); accum8(acc, x1); accum8(acc, x2); accum8(acc, x3);
            }
            // tail: <=3 groups of 4 edges (wave-uniform trip count)
            for (; e < wend; e += 4) {
                int q = e - w;
                int s = __shfl(idxreg, q + sub);
                uint4 x = *(const uint4*)(hin + (size_t)s * D + col * 8);
                accum8(acc, x);
            }
        }
#pragma unroll
        for (int j = 0; j < 8; j++) {
            acc[j] += __shfl_xor(acc[j], 16);
            acc[j] += __shfl_xor(acc[j], 32);
        }
        if (sub == 0) {
            int d2 = dgr; if (d2 < 1) d2 = 1;
            float s = rsqrtf((float)d2);
            uint4 o;
            o.x = (unsigned int)f2bf(acc[0] * s) | ((unsigned int)f2bf(acc[1] * s) << 16);
            o.y = (unsigned int)f2bf(acc[2] * s) | ((unsigned int)f2bf(acc[3] * s) << 16);
            o.z = (unsigned int)f2bf(acc[4] * s) | ((unsigned int)f2bf(acc[5] * s) << 16);
            o.w = (unsigned int)f2bf(acc[6] * s) | ((unsigned int)f2bf(acc[7] * s) << 16);
            *(uint4*)((char*)lA + aswz(r, col * 16)) = o;
        }
    }
    __syncthreads();

    // ---- phase B: MFMA GEMM; 4 waves = 4 row-tiles; 2 N-half passes keep VGPR <= 64 ----
    int row0 = b * 64 + wave * 16;
    float nsv[4];
    if (Cb) {
#pragma unroll
        for (int r = 0; r < 4; r++) {
            int rr = row0 + sub * 4 + r;
            nsv[r] = (rr < M) ? nsp[rr] : 1.f;
        }
    }
#pragma unroll
    for (int half = 0; half < 2; half++) {
        f32x4 acc2[4];
#pragma unroll
        for (int i = 0; i < 4; i++) acc2[i] = (f32x4){0.f, 0.f, 0.f, 0.f};
        int lr = wave * 16 + col;
#pragma unroll
        for (int kc = 0; kc < 4; kc++) {
            bf16x8 af = *(const bf16x8*)((const char*)lA + aswz(lr, kc * 64 + sub * 16));
#pragma unroll
            for (int j = 0; j < 4; j++) {
                int nt = half * 4 + j;
                bf16x8 bfr = *(const bf16x8*)(Wt + ((size_t)(kc * 8 + nt) * 64 + lane) * 8);
                acc2[j] = __builtin_amdgcn_mfma_f32_16x16x32_bf16(af, bfr, acc2[j], 0, 0, 0);
            }
        }
#pragma unroll
        for (int j = 0; j < 4; j++) {
            int nt = half * 4 + j;
            float bv = bias[nt * 16 + col];
#pragma unroll
            for (int r = 0; r < 4; r++) {
                int rr = row0 + sub * 4 + r;
                if (rr < M) {
                    float v = acc2[j][r] + bv;
                    if (Cf) {
                        Cf[(size_t)rr * D + nt * 16 + col] = v;
                    } else {
                        v = fmaxf(v, 0.f) * nsv[r];
                        Cb[(size_t)rr * D + nt * 16 + col] = f2bf(v);
                    }
                }
            }
        }
    }
}

extern "C" void kernel_launch(void* const* d_in, const int* in_sizes, int n_in,
                              void* d_out, int out_size, void* d_ws, size_t ws_size,
                              hipStream_t stream) {
    const float* x  = (const float*)d_in[0];
    const int* src = (const int*)d_in[1];
    const int* dst = (const int*)d_in[2];
    const float* Wl[3] = {(const float*)d_in[3], (const float*)d_in[5], (const float*)d_in[7]};
    const float* Bl[3] = {(const float*)d_in[4], (const float*)d_in[6], (const float*)d_in[8]};

    const int N = N_NODES;
    const int Mpad = ((N + 63) / 64) * 64;   // 100032 rows (includes SENT row)
    const size_t HBYTES = (size_t)Mpad * D * 2;  // 25,608,192

    char* ws = (char*)d_ws;

    // ---- aliased region: hB overlays preprocessing buffers that die before layer 0 writes hB ----
    unsigned short* hB = (unsigned short*)ws;                 // [0, HBYTES)
    int* cntD = (int*)ws;                                     // 3.2 MB
    int* cntS = (int*)(ws + (size_t)SCANL * 4);               // 3.2 MB
    unsigned int*  pairD = (unsigned int*)(ws + (size_t)2 * SCANL * 4);                       // 6.4 MB
    unsigned char* srcS  = (unsigned char*)(ws + (size_t)2 * SCANL * 4 + (size_t)N_EDGES * 4); // 1.6 MB
    int* bs = (int*)(ws + (size_t)2 * SCANL * 4 + (size_t)N_EDGES * 5);                        // 12.5 KB
    // total aliased use: ~14.42 MB < HBYTES ✓ (all dead after k_bsortpad/k_normsrc)

    // ---- persistent region after hB ----
    size_t o = HBYTES;
    auto take = [&](size_t bytes) -> void* {
        o = (o + 255) & ~(size_t)255;
        void* p = ws + o;
        o += bytes;
        return p;
    };
    float* norm_src = (float*)take((size_t)N * 4);
    int*   esrc     = (int*)take((size_t)(ECAP_PAD + 256) * 4);  // +256 window-read slack
    int*   rowbeg   = (int*)take((size_t)N * 4);
    int*   degD     = (int*)take((size_t)N * 4);
    unsigned short* Wt = (unsigned short*)take((size_t)3 * 128 * 128 * 2);
    unsigned short* hA = (unsigned short*)take(HBYTES);

    // partition preprocessing (LDS atomics only; no scan3 pass — offsets folded into consumers)
    k_pcount<<<PB, 1024, 0, stream>>>(src, dst, cntD, cntS);
    k_scanDS1<<<2 * SGRID, 256, 0, stream>>>(cntD, cntS, bs);
    k_scan2two<<<2, 1024, 0, stream>>>(bs);
    k_pscatter<<<PB, 1024, 0, stream>>>(src, dst, cntD, cntS, bs, pairD, srcS);
    k_normsrc<<<NB, 256, 0, stream>>>(srcS, cntS, bs, norm_src);
    // per-bucket counting sort -> padded CSR (pad-4, sentinel-filled, coalesced writes)
    k_bsortpad<<<NB, 256, 0, stream>>>(pairD, cntD, bs, esrc, rowbeg, degD);

    // x (fp32) * norm_src -> bf16; also zero SENT rows of hA/hB
    k_cvt<<<(N * 32 + 64 + 255) / 256, 256, 0, stream>>>(x, norm_src, hA, hB, N * 32);
    // all three weight transposes in one launch
    k_transw3<<<24, 256, 0, stream>>>(Wl[0], Wl[1], Wl[2], Wt);

    // fused layers: gather + GEMM + activation(+prescale) per launch
    k_fused<<<NB, 256, 0, stream>>>(hA, esrc, rowbeg, degD, norm_src, Wt,         Bl[0], hB, nullptr, N);
    k_fused<<<NB, 256, 0, stream>>>(hB, esrc, rowbeg, degD, norm_src, Wt + 16384, Bl[1], hA, nullptr, N);
    k_fused<<<NB, 256, 0, stream>>>(hA, esrc, rowbeg, degD, norm_src, Wt + 32768, Bl[2], nullptr, (float*)d_out, N);
}

// Round 9
// 370.479 us; speedup vs baseline: 1.1054x; 1.0131x over previous
//
#include <hip/hip_runtime.h>
#include <hip/hip_bf16.h>

#define N_NODES 100000
#define N_EDGES 1600000
#define D 128
#define NB 1563            // ceil(100000/64) buckets of 64 nodes
#define PB 512             // partition blocks
#define CHUNK 3125         // PB*CHUNK == N_EDGES
#define SCANL (NB * PB)    // 800256 count-matrix elements
#define SGRID (SCANL / 512) // 1563 scan blocks per array (512 elems/block); == NB since PB==512
#define SENT N_NODES       // sentinel (zero) row index
#define ECAP_PAD (N_EDGES + 256 * NB)  // 2000128: padded CSR capacity (pad-4 slack <= 192/bucket)
#define BCAP 2816          // LDS staging capacity per bucket in k_prep sort

typedef __attribute__((ext_vector_type(8))) short bf16x8;
typedef __attribute__((ext_vector_type(4))) float f32x4;

__device__ __forceinline__ float bf2f(unsigned short u) {
    unsigned int x = ((unsigned int)u) << 16;
    return __builtin_bit_cast(float, x);
}
__device__ __forceinline__ unsigned short f2bf(float f) {
    unsigned int x = __builtin_bit_cast(unsigned int, f);
    x += 0x7fffu + ((x >> 16) & 1u);   // round-to-nearest-even
    return (unsigned short)(x >> 16);
}
__device__ __forceinline__ void accum8(float* acc, uint4 x) {
    acc[0] += bf2f((unsigned short)x.x); acc[1] += bf2f((unsigned short)(x.x >> 16));
    acc[2] += bf2f((unsigned short)x.y); acc[3] += bf2f((unsigned short)(x.y >> 16));
    acc[4] += bf2f((unsigned short)x.z); acc[5] += bf2f((unsigned short)(x.z >> 16));
    acc[6] += bf2f((unsigned short)x.w); acc[7] += bf2f((unsigned short)(x.w >> 16));
}
// column permutation: co-XCD blocks (b%8 equal under round-robin dispatch) get adjacent
// count-matrix columns, so partial-line accesses stay XCD-local.
__device__ __forceinline__ int XP(int b) { return ((b & 7) << 6) | (b >> 3); }

// ---- P1: per-block LDS bucket histograms (dst>>6 and src>>6), no global atomics ----
__global__ __launch_bounds__(1024) void k_pcount(const int* __restrict__ src, const int* __restrict__ dst,
                                                 int* __restrict__ cntD, int* __restrict__ cntS) {
    __shared__ int hd[NB];
    __shared__ int hs[NB];
    int t = threadIdx.x, blk = blockIdx.x;
    int col = XP(blk);
    for (int i = t; i < NB; i += 1024) { hd[i] = 0; hs[i] = 0; }
    __syncthreads();
    int base = blk * CHUNK;
    for (int i = t; i < CHUNK; i += 1024) {
        int e = base + i;
        atomicAdd(&hd[dst[e] >> 6], 1);
        atomicAdd(&hs[src[e] >> 6], 1);
    }
    __syncthreads();
    for (int i = t; i < NB; i += 1024) {
        cntD[i * PB + col] = hd[i];
        cntS[i * PB + col] = hs[i];
    }
}

// ---- fused D+S exclusive scan pass 1; 512 elements per block; bs[blk] = block total ----
__global__ void k_scanDS1(int* __restrict__ cntD, int* __restrict__ cntS, int* __restrict__ bs) {
    __shared__ int tmp[256];
    int t = threadIdx.x;
    int which = (blockIdx.x >= SGRID) ? 1 : 0;
    int blk = blockIdx.x - which * SGRID;
    int* a = which ? cntS : cntD;
    int base = blk * 512;
    int a0 = a[base + 2 * t], a1 = a[base + 2 * t + 1];
    int s = a0 + a1;
    tmp[t] = s; __syncthreads();
    for (int off = 1; off < 256; off <<= 1) {
        int x = (t >= off) ? tmp[t - off] : 0;
        __syncthreads();
        tmp[t] += x;
        __syncthreads();
    }
    int excl = tmp[t] - s;
    a[base + 2 * t] = excl;
    a[base + 2 * t + 1] = excl + a0;
    if (t == 255) bs[blockIdx.x] = tmp[255];
}

__global__ void k_scan2two(int* __restrict__ bs) {  // 2 blocks, 1024 threads; each scans SGRID entries
    __shared__ int tmp[1024];
    int t = threadIdx.x;
    int base = blockIdx.x * SGRID;
    int i0 = 2 * t, i1 = 2 * t + 1;
    int a = (i0 < SGRID) ? bs[base + i0] : 0;
    int b = (i1 < SGRID) ? bs[base + i1] : 0;
    int s = a + b;
    tmp[t] = s; __syncthreads();
    for (int off = 1; off < 1024; off <<= 1) {
        int x = (t >= off) ? tmp[t - off] : 0;
        __syncthreads();
        tmp[t] += x;
        __syncthreads();
    }
    int excl = tmp[t] - s;
    if (i0 < SGRID) bs[base + i0] = excl;
    if (i1 < SGRID) bs[base + i1] = excl + a;
}

// NOTE: no scanDS3 pass — since PB==512, scan-block i covers matrix rows [i*512,(i+1)*512),
// so consumers fold the block offset: scanD[i*PB+col] + bsD[i].

// ---- P2: scatter edges into bucket order; positions from scanned matrices + LDS cursors ----
__global__ __launch_bounds__(1024) void k_pscatter(const int* __restrict__ src, const int* __restrict__ dst,
                                                   const int* __restrict__ scanD, const int* __restrict__ scanS,
                                                   const int* __restrict__ bs,
                                                   unsigned int* __restrict__ pairD, unsigned char* __restrict__ srcS) {
    __shared__ int od[NB];
    __shared__ int osx[NB];
    int t = threadIdx.x, blk = blockIdx.x;
    int col = XP(blk);
    for (int i = t; i < NB; i += 1024) {
        od[i] = scanD[i * PB + col] + bs[i];
        osx[i] = scanS[i * PB + col] + bs[SGRID + i];
    }
    __syncthreads();
    int base = blk * CHUNK;
    for (int i = t; i < CHUNK; i += 1024) {
        int e = base + i;
        int s = src[e], d = dst[e];
        int pd = atomicAdd(&od[d >> 6], 1);
        pairD[pd] = ((unsigned int)(d & 63) << 26) | (unsigned int)s;
        int ps = atomicAdd(&osx[s >> 6], 1);
        srcS[ps] = (unsigned char)(s & 63);
    }
}

// ---- merged prep (per bucket b): out-degree->norm_src, cvt own 64 x-rows -> hA,
//      counting sort -> padded CSR; blocks 0..23 also transpose W; block 0 zeroes SENT rows ----
__global__ __launch_bounds__(256) void k_prep(
        const unsigned int* __restrict__ pairD, const unsigned char* __restrict__ srcS,
        const int* __restrict__ scanD, const int* __restrict__ scanS, const int* __restrict__ bs,
        const float* __restrict__ x,
        const float* __restrict__ W0, const float* __restrict__ W1, const float* __restrict__ W2,
        int* __restrict__ esrc, int* __restrict__ rowbeg, int* __restrict__ degD,
        float* __restrict__ norm_src, unsigned short* __restrict__ Wt,
        unsigned short* __restrict__ hA, unsigned short* __restrict__ hB) {
    __shared__ int c[64];
    __shared__ float nsl[64];
    __shared__ int cnt[64], off[64], cur[64];
    __shared__ int ptotS;
    __shared__ int stage[BCAP];
    int b = blockIdx.x, t = threadIdx.x;
    int lane = t & 63, wave = t >> 6;

    // --- weight transpose (blocks 0..23 cover 3 layers x 2048 groups of 8) ---
    if (b < 24) {
        int gid = b * 256 + t;
        int layer = gid >> 11;
        int di8   = gid & 2047;
        const float* W = (layer == 0) ? W0 : ((layer == 1) ? W1 : W2);
        int di   = di8 * 8;
        int wl   = di8 & 63;
        int nt   = (di8 >> 6) & 7;
        int kc   = di8 >> 9;
        int quad = wl >> 4, wcol = wl & 15;
        unsigned short v[8];
#pragma unroll
        for (int j = 0; j < 8; j++) {
            int k = kc * 32 + quad * 8 + j;
            v[j] = f2bf(W[k * 128 + nt * 16 + wcol]);
        }
        unsigned short* dp = Wt + (size_t)layer * 16384 + di;
#pragma unroll
        for (int j = 0; j < 8; j++) dp[j] = v[j];
    }
    // --- sentinel rows of hA/hB (block 0); safe: offset 25.6MB is beyond aliased buffers ---
    if (b == 0 && t < 32) {
        uint4 z = {0u, 0u, 0u, 0u};
        if (t < 16) ((uint4*)(hA + (size_t)SENT * D))[t] = z;
        else        ((uint4*)(hB + (size_t)SENT * D))[t - 16] = z;
    }

    // --- phase 1: out-degree histogram -> norm_src (this bucket's 64 src nodes) ---
    if (t < 64) c[t] = 0;
    __syncthreads();
    int begS = scanS[b * PB] + bs[SGRID + b];
    int endS = (b < NB - 1) ? (scanS[(b + 1) * PB] + bs[SGRID + b + 1]) : N_EDGES;
    for (int i = begS + t; i < endS; i += 256) atomicAdd(&c[srcS[i]], 1);
    __syncthreads();
    if (t < 64) {
        int g = b * 64 + t;
        float nv = 1.f;
        if (g < N_NODES) {
            int a = c[t]; if (a < 1) a = 1;
            nv = rsqrtf((float)a);
            norm_src[g] = nv;
        }
        nsl[t] = nv;
    }
    __syncthreads();

    // --- phase 2: cvt this bucket's 64 rows of x (fp32) -> hA (bf16, pre-scaled) ---
    for (int i = t; i < 2048; i += 256) {       // 64 rows x 32 float4
        int row = b * 64 + (i >> 5);
        if (row < N_NODES) {
            float sc = nsl[i >> 5];
            const float4 v = ((const float4*)x)[(size_t)row * 32 + (i & 31)];
            unsigned int lo = (unsigned int)f2bf(v.x * sc) | ((unsigned int)f2bf(v.y * sc) << 16);
            unsigned int hi = (unsigned int)f2bf(v.z * sc) | ((unsigned int)f2bf(v.w * sc) << 16);
            ((uint2*)hA)[(size_t)row * 32 + (i & 31)] = make_uint2(lo, hi);
        }
    }

    // --- phase 3: per-bucket counting sort -> padded CSR (pad-4, sentinel-filled) ---
    if (t < 64) cnt[t] = 0;
    __syncthreads();
    int beg = scanD[b * PB] + bs[b];
    int end = (b < NB - 1) ? (scanD[(b + 1) * PB] + bs[b + 1]) : N_EDGES;
    int n = end - beg;
    int base = beg + 256 * b;   // per-bucket region with 256-slot pad slack
    for (int i = t; i < n; i += 256) atomicAdd(&cnt[pairD[beg + i] >> 26], 1);
    __syncthreads();
    if (wave == 0) {
        int v = cnt[lane];
        int pc = (v + 3) & ~3;            // pad each row to multiple of 4
        int xx = pc;
        for (int o = 1; o < 64; o <<= 1) { int y = __shfl_up(xx, o); if (lane >= o) xx += y; }
        off[lane] = xx - pc;
        cur[lane] = xx - pc;
        if (lane == 63) ptotS = xx;       // padded total for this bucket
    }
    __syncthreads();
    int ptot = ptotS; if (ptot > BCAP) ptot = BCAP;
    if (t < 64) {
        int g = b * 64 + t;
        if (g < N_NODES) { rowbeg[g] = base + off[t]; degD[g] = cnt[t]; }
    }
    for (int i = t; i < ptot; i += 256) stage[i] = SENT;   // sentinel pre-fill
    __syncthreads();
    for (int i = t; i < n; i += 256) {
        unsigned int p = pairD[beg + i];
        int pos = atomicAdd(&cur[p >> 26], 1);
        if (pos < BCAP) stage[pos] = (int)(p & 0x3FFFFFFu);
    }
    __syncthreads();
    for (int i = t; i < ptot; i += 256) esrc[base + i] = stage[i];   // coalesced write-out
}

// swizzled A-tile byte address: row-major [64][128] bf16, 16B blocks XOR'd by (row&7)
__device__ __forceinline__ int aswz(int row, int byte16) {
    return row * 256 + (byte16 ^ ((row & 7) << 4));
}

// ---- fused layer: reg-window gather with NEXT-ROW index prefetch -> LDS A-tile -> MFMA ----
// 256 threads, 16.9KB LDS -> 8 blocks/CU. Prefetch hides the per-row serial esrc load
// (the only change vs round 8's 72.4us control).
__global__ __launch_bounds__(256, 8) void k_fused(const unsigned short* __restrict__ hin,
        const int* __restrict__ esrc, const int* __restrict__ rowbeg, const int* __restrict__ degD,
        const float* __restrict__ nsp,
        const unsigned short* __restrict__ Wt, const float* __restrict__ bias,
        unsigned short* __restrict__ Cb, float* __restrict__ Cf, int M) {
    __shared__ int rb[64];
    __shared__ int dgt[64];
    __shared__ unsigned short lA[64 * 128];
    int b = blockIdx.x, t = threadIdx.x;
    int lane = t & 63, wave = t >> 6;          // wave 0..3
    int sub = lane >> 4, col = lane & 15;

    if (t < 64) {
        int g = b * 64 + t;
        rb[t]  = (g < M) ? rowbeg[g] : 0;
        dgt[t] = (g < M) ? degD[g] : 0;
    }
    __syncthreads();

    // ---- phase A: wave-per-row gather (pad-4, sentinel row = zeros), idx prefetched ----
    int r = wave;
    int ro = rb[r], dgr = dgt[r];
    int re = ro + ((dgr + 3) & ~3);
    int idxreg = (ro + lane < re) ? esrc[ro + lane] : 0;   // first row's window
    for (int k = 0; k < 16; k++, r += 4) {
        // prefetch next row's first window while gathering this row
        int nro = 0, ndgr = 0, nre = 0, nidx = 0;
        if (k < 15) {
            nro = rb[r + 4]; ndgr = dgt[r + 4];
            nre = nro + ((ndgr + 3) & ~3);
            nidx = (nro + lane < nre) ? esrc[nro + lane] : 0;
        }
        float acc[8];
#pragma unroll
        for (int j = 0; j < 8; j++) acc[j] = 0.f;
        int w = ro;
        int wend = (w + 64 < re) ? (w + 64) : re;
        int e = w;
        while (true) {
            for (; e + 16 <= wend; e += 16) {
                int q = e - w;
                int s0 = __shfl(idxreg, q + sub);
                int s1 = __shfl(idxreg, q + 4 + sub);
                int s2 = __shfl(idxreg, q + 8 + sub);
                int s3 = __shfl(idxreg, q + 12 + sub);
                uint4 x0 = *(const uint4*)(hin + (size_t)s0 * D + col * 8);
                uint4 x1 = *(const uint4*)(hin + (size_t)s1 * D + col * 8);
                uint4 x2 = *(const uint4*)(hin + (size_t)s2 * D + col * 8);
                uint4 x3 = *(const uint4*)(hin + (size_t)s3 * D + col * 8);
                accum8(acc, x0); accum8(acc, x1); accum8(acc, x2); accum8(acc, x3);
            }
            for (; e < wend; e += 4) {       // tail: <=3 groups of 4 (wave-uniform)
                int q = e - w;
                int s = __shfl(idxreg, q + sub);
                uint4 x = *(const uint4*)(hin + (size_t)s * D + col * 8);
                accum8(acc, x);
            }
            if (wend >= re) break;           // deg > 64: load further windows inline (rare)
            w = wend;
            idxreg = (w + lane < re) ? esrc[w + lane] : 0;
            wend = (w + 64 < re) ? (w + 64) : re;
        }
#pragma unroll
        for (int j = 0; j < 8; j++) {
            acc[j] += __shfl_xor(acc[j], 16);
            acc[j] += __shfl_xor(acc[j], 32);
        }
        if (sub == 0) {
            int d2 = dgr; if (d2 < 1) d2 = 1;
            float s = rsqrtf((float)d2);
            uint4 o;
            o.x = (unsigned int)f2bf(acc[0] * s) | ((unsigned int)f2bf(acc[1] * s) << 16);
            o.y = (unsigned int)f2bf(acc[2] * s) | ((unsigned int)f2bf(acc[3] * s) << 16);
            o.z = (unsigned int)f2bf(acc[4] * s) | ((unsigned int)f2bf(acc[5] * s) << 16);
            o.w = (unsigned int)f2bf(acc[6] * s) | ((unsigned int)f2bf(acc[7] * s) << 16);
            *(uint4*)((char*)lA + aswz(r, col * 16)) = o;
        }
        ro = nro; dgr = ndgr; re = nre; idxreg = nidx;     // rotate prefetched state
    }
    __syncthreads();

    // ---- phase B: MFMA GEMM; 4 waves = 4 row-tiles; 2 N-half passes keep VGPR <= 64 ----
    int row0 = b * 64 + wave * 16;
    float nsv[4];
    if (Cb) {
#pragma unroll
        for (int rr4 = 0; rr4 < 4; rr4++) {
            int rr = row0 + sub * 4 + rr4;
            nsv[rr4] = (rr < M) ? nsp[rr] : 1.f;
        }
    }
#pragma unroll
    for (int half = 0; half < 2; half++) {
        f32x4 acc2[4];
#pragma unroll
        for (int i = 0; i < 4; i++) acc2[i] = (f32x4){0.f, 0.f, 0.f, 0.f};
        int lr = wave * 16 + col;
#pragma unroll
        for (int kc = 0; kc < 4; kc++) {
            bf16x8 af = *(const bf16x8*)((const char*)lA + aswz(lr, kc * 64 + sub * 16));
#pragma unroll
            for (int j = 0; j < 4; j++) {
                int nt = half * 4 + j;
                bf16x8 bfr = *(const bf16x8*)(Wt + ((size_t)(kc * 8 + nt) * 64 + lane) * 8);
                acc2[j] = __builtin_amdgcn_mfma_f32_16x16x32_bf16(af, bfr, acc2[j], 0, 0, 0);
            }
        }
#pragma unroll
        for (int j = 0; j < 4; j++) {
            int nt = half * 4 + j;
            float bv = bias[nt * 16 + col];
#pragma unroll
            for (int rr4 = 0; rr4 < 4; rr4++) {
                int rr = row0 + sub * 4 + rr4;
                if (rr < M) {
                    float v = acc2[j][rr4] + bv;
                    if (Cf) {
                        Cf[(size_t)rr * D + nt * 16 + col] = v;
                    } else {
                        v = fmaxf(v, 0.f) * nsv[rr4];
                        Cb[(size_t)rr * D + nt * 16 + col] = f2bf(v);
                    }
                }
            }
        }
    }
}

extern "C" void kernel_launch(void* const* d_in, const int* in_sizes, int n_in,
                              void* d_out, int out_size, void* d_ws, size_t ws_size,
                              hipStream_t stream) {
    const float* x  = (const float*)d_in[0];
    const int* src = (const int*)d_in[1];
    const int* dst = (const int*)d_in[2];
    const float* Wl[3] = {(const float*)d_in[3], (const float*)d_in[5], (const float*)d_in[7]};
    const float* Bl[3] = {(const float*)d_in[4], (const float*)d_in[6], (const float*)d_in[8]};

    const int N = N_NODES;
    const int Mpad = ((N + 63) / 64) * 64;   // 100032 rows (includes SENT row)
    const size_t HBYTES = (size_t)Mpad * D * 2;  // 25,608,192

    char* ws = (char*)d_ws;

    // ---- aliased region: hB overlays preprocessing buffers that die before layer 0 writes hB ----
    unsigned short* hB = (unsigned short*)ws;                 // [0, HBYTES)
    int* cntD = (int*)ws;                                     // 3.2 MB
    int* cntS = (int*)(ws + (size_t)SCANL * 4);               // 3.2 MB
    unsigned int*  pairD = (unsigned int*)(ws + (size_t)2 * SCANL * 4);                       // 6.4 MB
    unsigned char* srcS  = (unsigned char*)(ws + (size_t)2 * SCANL * 4 + (size_t)N_EDGES * 4); // 1.6 MB
    int* bs = (int*)(ws + (size_t)2 * SCANL * 4 + (size_t)N_EDGES * 5);                        // 12.5 KB
    // total aliased use: ~14.42 MB < HBYTES ✓ (all dead after k_prep; hB sentinel row @25.6MB is outside)

    // ---- persistent region after hB ----
    size_t o = HBYTES;
    auto take = [&](size_t bytes) -> void* {
        o = (o + 255) & ~(size_t)255;
        void* p = ws + o;
        o += bytes;
        return p;
    };
    float* norm_src = (float*)take((size_t)N * 4);
    int*   esrc     = (int*)take((size_t)(ECAP_PAD + 256) * 4);  // +256 window-read slack
    int*   rowbeg   = (int*)take((size_t)N * 4);
    int*   degD     = (int*)take((size_t)N * 4);
    unsigned short* Wt = (unsigned short*)take((size_t)3 * 128 * 128 * 2);
    unsigned short* hA = (unsigned short*)take(HBYTES);

    // partition preprocessing (LDS atomics only; no scan3 pass — offsets folded into consumers)
    k_pcount<<<PB, 1024, 0, stream>>>(src, dst, cntD, cntS);
    k_scanDS1<<<2 * SGRID, 256, 0, stream>>>(cntD, cntS, bs);
    k_scan2two<<<2, 1024, 0, stream>>>(bs);
    k_pscatter<<<PB, 1024, 0, stream>>>(src, dst, cntD, cntS, bs, pairD, srcS);
    // merged: norm_src + cvt + counting sort + weight transpose + sentinel zero
    k_prep<<<NB, 256, 0, stream>>>(pairD, srcS, cntD, cntS, bs, x,
                                   Wl[0], Wl[1], Wl[2],
                                   esrc, rowbeg, degD, norm_src, Wt, hA, hB);

    // fused layers: gather + GEMM + activation(+prescale) per launch
    k_fused<<<NB, 256, 0, stream>>>(hA, esrc, rowbeg, degD, norm_src, Wt,         Bl[0], hB, nullptr, N);
    k_fused<<<NB, 256, 0, stream>>>(hB, esrc, rowbeg, degD, norm_src, Wt + 16384, Bl[1], hA, nullptr, N);
    k_fused<<<NB, 256, 0, stream>>>(hA, esrc, rowbeg, degD, norm_src, Wt + 32768, Bl[2], nullptr, (float*)d_out, N);
}

// Round 10
// 368.704 us; speedup vs baseline: 1.1107x; 1.0048x over previous
//
#include <hip/hip_runtime.h>
#include <hip/hip_bf16.h>

#define N_NODES 100000
#define N_EDGES 1600000
#define D 128
#define NB 1563            // ceil(100000/64) buckets of 64 nodes
#define PB 128             // partition blocks (dense runs: ~8 edges per (bucket,block))
#define CHUNK 12500        // PB*CHUNK == N_EDGES
#define SCANL (NB * PB)    // 200064 count-matrix elements
#define SGRID 391          // ceil(SCANL/512) scan blocks per array
#define SENT N_NODES       // sentinel (zero) row index
#define ECAP_PAD (N_EDGES + 256 * NB)  // 2000128: padded CSR capacity (pad-4 slack <= 192/bucket)
#define BCAP 2816          // LDS staging capacity per bucket in k_prep sort

typedef __attribute__((ext_vector_type(8))) short bf16x8;
typedef __attribute__((ext_vector_type(4))) float f32x4;

__device__ __forceinline__ float bf2f(unsigned short u) {
    unsigned int x = ((unsigned int)u) << 16;
    return __builtin_bit_cast(float, x);
}
__device__ __forceinline__ unsigned short f2bf(float f) {
    unsigned int x = __builtin_bit_cast(unsigned int, f);
    x += 0x7fffu + ((x >> 16) & 1u);   // round-to-nearest-even
    return (unsigned short)(x >> 16);
}
__device__ __forceinline__ void accum8(float* acc, uint4 x) {
    acc[0] += bf2f((unsigned short)x.x); acc[1] += bf2f((unsigned short)(x.x >> 16));
    acc[2] += bf2f((unsigned short)x.y); acc[3] += bf2f((unsigned short)(x.y >> 16));
    acc[4] += bf2f((unsigned short)x.z); acc[5] += bf2f((unsigned short)(x.z >> 16));
    acc[6] += bf2f((unsigned short)x.w); acc[7] += bf2f((unsigned short)(x.w >> 16));
}
// column permutation for PB=128: 16 consecutive columns belong to one XCD
// (blocks round-robin XCDs by b%8), so each 64B count-matrix line is XCD-private.
__device__ __forceinline__ int XP(int b) { return ((b & 7) << 4) | (b >> 3); }

// ---- P1: per-block LDS bucket histograms (dst>>6 and src>>6), no global atomics ----
__global__ __launch_bounds__(1024) void k_pcount(const int* __restrict__ src, const int* __restrict__ dst,
                                                 int* __restrict__ cntD, int* __restrict__ cntS) {
    __shared__ int hd[NB];
    __shared__ int hs[NB];
    int t = threadIdx.x, blk = blockIdx.x;
    int col = XP(blk);
    for (int i = t; i < NB; i += 1024) { hd[i] = 0; hs[i] = 0; }
    __syncthreads();
    int base = blk * CHUNK;
    for (int i = t; i < CHUNK; i += 1024) {
        int e = base + i;
        atomicAdd(&hd[dst[e] >> 6], 1);
        atomicAdd(&hs[src[e] >> 6], 1);
    }
    __syncthreads();
    for (int i = t; i < NB; i += 1024) {
        cntD[i * PB + col] = hd[i];
        cntS[i * PB + col] = hs[i];
    }
}

// ---- fused D+S exclusive scan pass 1; 512 elements per block (tail-guarded) ----
__global__ void k_scanDS1(int* __restrict__ cntD, int* __restrict__ cntS, int* __restrict__ bs) {
    __shared__ int tmp[256];
    int t = threadIdx.x;
    int which = (blockIdx.x >= SGRID) ? 1 : 0;
    int blk = blockIdx.x - which * SGRID;
    int* a = which ? cntS : cntD;
    int g0 = blk * 512 + 2 * t, g1 = g0 + 1;
    int a0 = (g0 < SCANL) ? a[g0] : 0;
    int a1 = (g1 < SCANL) ? a[g1] : 0;
    int s = a0 + a1;
    tmp[t] = s; __syncthreads();
    for (int off = 1; off < 256; off <<= 1) {
        int x = (t >= off) ? tmp[t - off] : 0;
        __syncthreads();
        tmp[t] += x;
        __syncthreads();
    }
    int excl = tmp[t] - s;
    if (g0 < SCANL) a[g0] = excl;
    if (g1 < SCANL) a[g1] = excl + a0;
    if (t == 255) bs[blockIdx.x] = tmp[255];
}

__global__ void k_scan2two(int* __restrict__ bs) {  // 2 blocks, 1024 threads; each scans SGRID entries
    __shared__ int tmp[1024];
    int t = threadIdx.x;
    int base = blockIdx.x * SGRID;
    int i0 = 2 * t, i1 = 2 * t + 1;
    int a = (i0 < SGRID) ? bs[base + i0] : 0;
    int b = (i1 < SGRID) ? bs[base + i1] : 0;
    int s = a + b;
    tmp[t] = s; __syncthreads();
    for (int off = 1; off < 1024; off <<= 1) {
        int x = (t >= off) ? tmp[t - off] : 0;
        __syncthreads();
        tmp[t] += x;
        __syncthreads();
    }
    int excl = tmp[t] - s;
    if (i0 < SGRID) bs[base + i0] = excl;
    if (i1 < SGRID) bs[base + i1] = excl + a;
}

// NOTE: no scan3 pass — element index of (bucket i, col c) is i*128+c, whose scan-block is
// (i*128+c)>>9 == i>>2 (since (i&3)*128+c < 512). Consumers fold: scanD[i*PB+col] + bs[i>>2].

// ---- P2: scatter edges into bucket order; positions from scanned matrices + LDS cursors ----
__global__ __launch_bounds__(1024) void k_pscatter(const int* __restrict__ src, const int* __restrict__ dst,
                                                   const int* __restrict__ scanD, const int* __restrict__ scanS,
                                                   const int* __restrict__ bs,
                                                   unsigned int* __restrict__ pairD, unsigned char* __restrict__ srcS) {
    __shared__ int od[NB];
    __shared__ int osx[NB];
    int t = threadIdx.x, blk = blockIdx.x;
    int col = XP(blk);
    for (int i = t; i < NB; i += 1024) {
        od[i] = scanD[i * PB + col] + bs[i >> 2];
        osx[i] = scanS[i * PB + col] + bs[SGRID + (i >> 2)];
    }
    __syncthreads();
    int base = blk * CHUNK;
    for (int i = t; i < CHUNK; i += 1024) {
        int e = base + i;
        int s = src[e], d = dst[e];
        int pd = atomicAdd(&od[d >> 6], 1);
        pairD[pd] = ((unsigned int)(d & 63) << 26) | (unsigned int)s;
        int ps = atomicAdd(&osx[s >> 6], 1);
        srcS[ps] = (unsigned char)(s & 63);
    }
}

// ---- merged prep (per bucket b): out-degree->norm_src, cvt own 64 x-rows -> hA,
//      counting sort -> padded CSR; blocks 0..23 also transpose W; block 0 zeroes SENT rows ----
__global__ __launch_bounds__(256) void k_prep(
        const unsigned int* __restrict__ pairD, const unsigned char* __restrict__ srcS,
        const int* __restrict__ scanD, const int* __restrict__ scanS, const int* __restrict__ bs,
        const float* __restrict__ x,
        const float* __restrict__ W0, const float* __restrict__ W1, const float* __restrict__ W2,
        int* __restrict__ esrc, int* __restrict__ rowbeg, int* __restrict__ degD,
        float* __restrict__ norm_src, unsigned short* __restrict__ Wt,
        unsigned short* __restrict__ hA, unsigned short* __restrict__ hB) {
    __shared__ int c[64];
    __shared__ float nsl[64];
    __shared__ int cnt[64], off[64], cur[64];
    __shared__ int ptotS;
    __shared__ int stage[BCAP];
    int b = blockIdx.x, t = threadIdx.x;
    int lane = t & 63, wave = t >> 6;

    // --- weight transpose (blocks 0..23 cover 3 layers x 2048 groups of 8) ---
    if (b < 24) {
        int gid = b * 256 + t;
        int layer = gid >> 11;
        int di8   = gid & 2047;
        const float* W = (layer == 0) ? W0 : ((layer == 1) ? W1 : W2);
        int di   = di8 * 8;
        int wl   = di8 & 63;
        int nt   = (di8 >> 6) & 7;
        int kc   = di8 >> 9;
        int quad = wl >> 4, wcol = wl & 15;
        unsigned short v[8];
#pragma unroll
        for (int j = 0; j < 8; j++) {
            int k = kc * 32 + quad * 8 + j;
            v[j] = f2bf(W[k * 128 + nt * 16 + wcol]);
        }
        unsigned short* dp = Wt + (size_t)layer * 16384 + di;
#pragma unroll
        for (int j = 0; j < 8; j++) dp[j] = v[j];
    }
    // --- sentinel rows of hA/hB (block 0); safe: offset 25.6MB is beyond aliased buffers ---
    if (b == 0 && t < 32) {
        uint4 z = {0u, 0u, 0u, 0u};
        if (t < 16) ((uint4*)(hA + (size_t)SENT * D))[t] = z;
        else        ((uint4*)(hB + (size_t)SENT * D))[t - 16] = z;
    }

    // --- phase 1: out-degree histogram -> norm_src (this bucket's 64 src nodes) ---
    if (t < 64) c[t] = 0;
    __syncthreads();
    int begS = scanS[b * PB] + bs[SGRID + (b >> 2)];
    int endS = (b < NB - 1) ? (scanS[(b + 1) * PB] + bs[SGRID + ((b + 1) >> 2)]) : N_EDGES;
    for (int i = begS + t; i < endS; i += 256) atomicAdd(&c[srcS[i]], 1);
    __syncthreads();
    if (t < 64) {
        int g = b * 64 + t;
        float nv = 1.f;
        if (g < N_NODES) {
            int a = c[t]; if (a < 1) a = 1;
            nv = rsqrtf((float)a);
            norm_src[g] = nv;
        }
        nsl[t] = nv;
    }
    __syncthreads();

    // --- phase 2: cvt this bucket's 64 rows of x (fp32) -> hA (bf16, pre-scaled) ---
    for (int i = t; i < 2048; i += 256) {       // 64 rows x 32 float4
        int row = b * 64 + (i >> 5);
        if (row < N_NODES) {
            float sc = nsl[i >> 5];
            const float4 v = ((const float4*)x)[(size_t)row * 32 + (i & 31)];
            unsigned int lo = (unsigned int)f2bf(v.x * sc) | ((unsigned int)f2bf(v.y * sc) << 16);
            unsigned int hi = (unsigned int)f2bf(v.z * sc) | ((unsigned int)f2bf(v.w * sc) << 16);
            ((uint2*)hA)[(size_t)row * 32 + (i & 31)] = make_uint2(lo, hi);
        }
    }

    // --- phase 3: per-bucket counting sort -> padded CSR (pad-4, sentinel-filled) ---
    if (t < 64) cnt[t] = 0;
    __syncthreads();
    int beg = scanD[b * PB] + bs[b >> 2];
    int end = (b < NB - 1) ? (scanD[(b + 1) * PB] + bs[(b + 1) >> 2]) : N_EDGES;
    int n = end - beg;
    int base = beg + 256 * b;   // per-bucket region with 256-slot pad slack
    for (int i = t; i < n; i += 256) atomicAdd(&cnt[pairD[beg + i] >> 26], 1);
    __syncthreads();
    if (wave == 0) {
        int v = cnt[lane];
        int pc = (v + 3) & ~3;            // pad each row to multiple of 4
        int xx = pc;
        for (int o = 1; o < 64; o <<= 1) { int y = __shfl_up(xx, o); if (lane >= o) xx += y; }
        off[lane] = xx - pc;
        cur[lane] = xx - pc;
        if (lane == 63) ptotS = xx;       // padded total for this bucket
    }
    __syncthreads();
    int ptot = ptotS; if (ptot > BCAP) ptot = BCAP;
    if (t < 64) {
        int g = b * 64 + t;
        if (g < N_NODES) { rowbeg[g] = base + off[t]; degD[g] = cnt[t]; }
    }
    for (int i = t; i < ptot; i += 256) stage[i] = SENT;   // sentinel pre-fill
    __syncthreads();
    for (int i = t; i < n; i += 256) {
        unsigned int p = pairD[beg + i];
        int pos = atomicAdd(&cur[p >> 26], 1);
        if (pos < BCAP) stage[pos] = (int)(p & 0x3FFFFFFu);
    }
    __syncthreads();
    for (int i = t; i < ptot; i += 256) esrc[base + i] = stage[i];   // coalesced write-out
}

// swizzled A-tile byte address: row-major [64][128] bf16, 16B blocks XOR'd by (row&7)
__device__ __forceinline__ int aswz(int row, int byte16) {
    return row * 256 + (byte16 ^ ((row & 7) << 4));
}

// ---- fused layer: reg-window gather (1-hop chain via shfl-staged indices) -> LDS A-tile ----
// BYTE-IDENTICAL to round-8 control (72.4 us; 16.9KB LDS, 8 blocks/CU; demand-bound at ~6.4 TB/s).
__global__ __launch_bounds__(256, 8) void k_fused(const unsigned short* __restrict__ hin,
        const int* __restrict__ esrc, const int* __restrict__ rowbeg, const int* __restrict__ degD,
        const float* __restrict__ nsp,
        const unsigned short* __restrict__ Wt, const float* __restrict__ bias,
        unsigned short* __restrict__ Cb, float* __restrict__ Cf, int M) {
    __shared__ int rb[64];
    __shared__ int dgt[64];
    __shared__ unsigned short lA[64 * 128];
    int b = blockIdx.x, t = threadIdx.x;
    int lane = t & 63, wave = t >> 6;          // wave 0..3
    int sub = lane >> 4, col = lane & 15;

    if (t < 64) {
        int g = b * 64 + t;
        rb[t]  = (g < M) ? rowbeg[g] : 0;
        dgt[t] = (g < M) ? degD[g] : 0;
    }
    __syncthreads();

    // ---- phase A: wave-per-row gather (padded to x4, sentinel row = zeros) ----
    for (int r = wave; r < 64; r += 4) {
        int ro = rb[r];
        int dgr = dgt[r];
        int re = ro + ((dgr + 3) & ~3);
        float acc[8];
#pragma unroll
        for (int j = 0; j < 8; j++) acc[j] = 0.f;
        int e = ro;
        while (e < re) {
            int w = e;                                   // 64-edge register window
            int wl = w + lane;
            int idxreg = (wl < re) ? esrc[wl] : 0;       // coalesced, exec-masked
            int wend = (w + 64 < re) ? (w + 64) : re;
            // main: 16 edges/iter, 4 uint4 in flight, indices via shfl (no global dep)
            for (; e + 16 <= wend; e += 16) {
                int q = e - w;
                int s0 = __shfl(idxreg, q + sub);
                int s1 = __shfl(idxreg, q + 4 + sub);
                int s2 = __shfl(idxreg, q + 8 + sub);
                int s3 = __shfl(idxreg, q + 12 + sub);
                uint4 x0 = *(const uint4*)(hin + (size_t)s0 * D + col * 8);
                uint4 x1 = *(const uint4*)(hin + (size_t)s1 * D + col * 8);
                uint4 x2 = *(const uint4*)(hin + (size_t)s2 * D + col * 8);
                uint4 x3 = *(const uint4*)(hin + (size_t)s3 * D + col * 8);
                accum8(acc, x0); accum8(acc, x1); accum8(acc, x2); accum8(acc, x3);
            }
            // tail: <=3 groups of 4 edges (wave-uniform trip count)
            for (; e < wend; e += 4) {
                int q = e - w;
                int s = __shfl(idxreg, q + sub);
                uint4 x = *(const uint4*)(hin + (size_t)s * D + col * 8);
                accum8(acc, x);
            }
        }
#pragma unroll
        for (int j = 0; j < 8; j++) {
            acc[j] += __shfl_xor(acc[j], 16);
            acc[j] += __shfl_xor(acc[j], 32);
        }
        if (sub == 0) {
            int d2 = dgr; if (d2 < 1) d2 = 1;
            float s = rsqrtf((float)d2);
            uint4 o;
            o.x = (unsigned int)f2bf(acc[0] * s) | ((unsigned int)f2bf(acc[1] * s) << 16);
            o.y = (unsigned int)f2bf(acc[2] * s) | ((unsigned int)f2bf(acc[3] * s) << 16);
            o.z = (unsigned int)f2bf(acc[4] * s) | ((unsigned int)f2bf(acc[5] * s) << 16);
            o.w = (unsigned int)f2bf(acc[6] * s) | ((unsigned int)f2bf(acc[7] * s) << 16);
            *(uint4*)((char*)lA + aswz(r, col * 16)) = o;
        }
    }
    __syncthreads();

    // ---- phase B: MFMA GEMM; 4 waves = 4 row-tiles; 2 N-half passes keep VGPR <= 64 ----
    int row0 = b * 64 + wave * 16;
    float nsv[4];
    if (Cb) {
#pragma unroll
        for (int r = 0; r < 4; r++) {
            int rr = row0 + sub * 4 + r;
            nsv[r] = (rr < M) ? nsp[rr] : 1.f;
        }
    }
#pragma unroll
    for (int half = 0; half < 2; half++) {
        f32x4 acc2[4];
#pragma unroll
        for (int i = 0; i < 4; i++) acc2[i] = (f32x4){0.f, 0.f, 0.f, 0.f};
        int lr = wave * 16 + col;
#pragma unroll
        for (int kc = 0; kc < 4; kc++) {
            bf16x8 af = *(const bf16x8*)((const char*)lA + aswz(lr, kc * 64 + sub * 16));
#pragma unroll
            for (int j = 0; j < 4; j++) {
                int nt = half * 4 + j;
                bf16x8 bfr = *(const bf16x8*)(Wt + ((size_t)(kc * 8 + nt) * 64 + lane) * 8);
                acc2[j] = __builtin_amdgcn_mfma_f32_16x16x32_bf16(af, bfr, acc2[j], 0, 0, 0);
            }
        }
#pragma unroll
        for (int j = 0; j < 4; j++) {
            int nt = half * 4 + j;
            float bv = bias[nt * 16 + col];
#pragma unroll
            for (int r = 0; r < 4; r++) {
                int rr = row0 + sub * 4 + r;
                if (rr < M) {
                    float v = acc2[j][r] + bv;
                    if (Cf) {
                        Cf[(size_t)rr * D + nt * 16 + col] = v;
                    } else {
                        v = fmaxf(v, 0.f) * nsv[r];
                        Cb[(size_t)rr * D + nt * 16 + col] = f2bf(v);
                    }
                }
            }
        }
    }
}

extern "C" void kernel_launch(void* const* d_in, const int* in_sizes, int n_in,
                              void* d_out, int out_size, void* d_ws, size_t ws_size,
                              hipStream_t stream) {
    const float* x  = (const float*)d_in[0];
    const int* src = (const int*)d_in[1];
    const int* dst = (const int*)d_in[2];
    const float* Wl[3] = {(const float*)d_in[3], (const float*)d_in[5], (const float*)d_in[7]};
    const float* Bl[3] = {(const float*)d_in[4], (const float*)d_in[6], (const float*)d_in[8]};

    const int N = N_NODES;
    const int Mpad = ((N + 63) / 64) * 64;   // 100032 rows (includes SENT row)
    const size_t HBYTES = (size_t)Mpad * D * 2;  // 25,608,192

    char* ws = (char*)d_ws;

    // ---- aliased region: hB overlays preprocessing buffers that die before layer 0 writes hB ----
    unsigned short* hB = (unsigned short*)ws;                 // [0, HBYTES)
    int* cntD = (int*)ws;                                     // 0.8 MB
    int* cntS = (int*)(ws + (size_t)SCANL * 4);               // 0.8 MB
    unsigned int*  pairD = (unsigned int*)(ws + (size_t)2 * SCANL * 4);                       // 6.4 MB
    unsigned char* srcS  = (unsigned char*)(ws + (size_t)2 * SCANL * 4 + (size_t)N_EDGES * 4); // 1.6 MB
    int* bs = (int*)(ws + (size_t)2 * SCANL * 4 + (size_t)N_EDGES * 5);                        // 3.1 KB
    // total aliased use: ~9.6 MB < HBYTES ✓ (all dead after k_prep; hB sentinel row @25.6MB is outside)

    // ---- persistent region after hB ----
    size_t o = HBYTES;
    auto take = [&](size_t bytes) -> void* {
        o = (o + 255) & ~(size_t)255;
        void* p = ws + o;
        o += bytes;
        return p;
    };
    float* norm_src = (float*)take((size_t)N * 4);
    int*   esrc     = (int*)take((size_t)(ECAP_PAD + 256) * 4);  // +256 window-read slack
    int*   rowbeg   = (int*)take((size_t)N * 4);
    int*   degD     = (int*)take((size_t)N * 4);
    unsigned short* Wt = (unsigned short*)take((size_t)3 * 128 * 128 * 2);
    unsigned short* hA = (unsigned short*)take(HBYTES);

    // partition preprocessing (LDS atomics only; PB=128 for dense write runs; no scan3 pass)
    k_pcount<<<PB, 1024, 0, stream>>>(src, dst, cntD, cntS);
    k_scanDS1<<<2 * SGRID, 256, 0, stream>>>(cntD, cntS, bs);
    k_scan2two<<<2, 1024, 0, stream>>>(bs);
    k_pscatter<<<PB, 1024, 0, stream>>>(src, dst, cntD, cntS, bs, pairD, srcS);
    // merged: norm_src + cvt + counting sort + weight transpose + sentinel zero
    k_prep<<<NB, 256, 0, stream>>>(pairD, srcS, cntD, cntS, bs, x,
                                   Wl[0], Wl[1], Wl[2],
                                   esrc, rowbeg, degD, norm_src, Wt, hA, hB);

    // fused layers: gather + GEMM + activation(+prescale) per launch
    k_fused<<<NB, 256, 0, stream>>>(hA, esrc, rowbeg, degD, norm_src, Wt,         Bl[0], hB, nullptr, N);
    k_fused<<<NB, 256, 0, stream>>>(hB, esrc, rowbeg, degD, norm_src, Wt + 16384, Bl[1], hA, nullptr, N);
    k_fused<<<NB, 256, 0, stream>>>(hA, esrc, rowbeg, degD, norm_src, Wt + 32768, Bl[2], nullptr, (float*)d_out, N);
}